// Round 1
// baseline (21994.026 us; speedup 1.0000x reference)
//
#include <hip/hip_runtime.h>
#include <hip/hip_bf16.h>
#include <math.h>

// Problem dims
#define T_ 70
#define B_ 128
#define E_ 400
#define H_ 1150
#define V_ 33278

// ---------------------------------------------------------------------------
// Embedding gather: out[tb][e] = table[tokens[tb]][e]
// ---------------------------------------------------------------------------
__global__ void emb_gather(const int* __restrict__ tokens,
                           const float* __restrict__ table,
                           float* __restrict__ out) {
    int tb = blockIdx.x;
    int tok = tokens[tb];
    const float2* src = (const float2*)(table + (size_t)tok * E_);
    float2* dst = (float2*)(out + (size_t)tb * E_);
    for (int e = threadIdx.x; e < E_ / 2; e += blockDim.x) {
        dst[e] = src[e];
    }
}

// ---------------------------------------------------------------------------
// SGEMM (NT): C[M,N] = A[M,K] @ W[N,K]^T + b1[N] + b2[N]
// A row-major [M,K], W row-major [N,K] (K-contiguous both: "NT" layout).
// 128x128 block tile, BK=8, 256 threads, 8x8 per thread (split 4+4 fragments).
// All global accesses are float2 (row strides are even, not mult-of-4).
// M must be a multiple of 128 (true here: 8960). N,K arbitrary even.
// ---------------------------------------------------------------------------
#define GBM 128
#define GBN 128
#define GBK 8

__global__ __launch_bounds__(256) void sgemm_nt(
    const float* __restrict__ A, const float* __restrict__ W,
    const float* __restrict__ b1, const float* __restrict__ b2,
    float* __restrict__ C, int M, int N, int K)
{
    __shared__ float As[GBK][GBM];
    __shared__ float Ws[GBK][GBN];
    const int tid = threadIdx.x;
    const int tx = tid & 15, ty = tid >> 4;
    const int bm0 = blockIdx.y * GBM, bn0 = blockIdx.x * GBN;

    float acc[8][8];
#pragma unroll
    for (int i = 0; i < 8; i++)
#pragma unroll
        for (int j = 0; j < 8; j++) acc[i][j] = 0.f;

    const int lr = tid >> 1;        // 0..127 (tile row / weight row)
    const int lk = (tid & 1) * 4;   // 0 or 4
    const float* Arow = A + (size_t)(bm0 + lr) * K + lk;
    const int wn = bn0 + lr;
    const bool wvalid = (wn < N);
    const float* Wrow = W + (size_t)(wvalid ? wn : 0) * K + lk;

    for (int k0 = 0; k0 < K; k0 += GBK) {
        const int kb = k0 + lk;
        float4 av = {0.f, 0.f, 0.f, 0.f};
        float4 wv = {0.f, 0.f, 0.f, 0.f};
        if (kb + 4 <= K) {
            float2 t0 = *(const float2*)(Arow + k0);
            float2 t1 = *(const float2*)(Arow + k0 + 2);
            av.x = t0.x; av.y = t0.y; av.z = t1.x; av.w = t1.y;
        } else if (kb + 2 <= K) {
            float2 t0 = *(const float2*)(Arow + k0);
            av.x = t0.x; av.y = t0.y;
        }
        if (wvalid) {
            if (kb + 4 <= K) {
                float2 t0 = *(const float2*)(Wrow + k0);
                float2 t1 = *(const float2*)(Wrow + k0 + 2);
                wv.x = t0.x; wv.y = t0.y; wv.z = t1.x; wv.w = t1.y;
            } else if (kb + 2 <= K) {
                float2 t0 = *(const float2*)(Wrow + k0);
                wv.x = t0.x; wv.y = t0.y;
            }
        }
        __syncthreads();
        As[lk + 0][lr] = av.x; As[lk + 1][lr] = av.y;
        As[lk + 2][lr] = av.z; As[lk + 3][lr] = av.w;
        Ws[lk + 0][lr] = wv.x; Ws[lk + 1][lr] = wv.y;
        Ws[lk + 2][lr] = wv.z; Ws[lk + 3][lr] = wv.w;
        __syncthreads();
#pragma unroll
        for (int kk = 0; kk < GBK; kk++) {
            float a[8], b[8];
            *(float4*)(a)     = *(const float4*)&As[kk][ty * 4];
            *(float4*)(a + 4) = *(const float4*)&As[kk][64 + ty * 4];
            *(float4*)(b)     = *(const float4*)&Ws[kk][tx * 4];
            *(float4*)(b + 4) = *(const float4*)&Ws[kk][64 + tx * 4];
#pragma unroll
            for (int i = 0; i < 8; i++)
#pragma unroll
                for (int j = 0; j < 8; j++) acc[i][j] += a[i] * b[j];
        }
    }

    // Epilogue: bias + store. N is always even here, cols[j] even for even j,
    // so float2 pairs are all-valid or all-invalid.
    int rows[8], cols[8];
#pragma unroll
    for (int i = 0; i < 8; i++) rows[i] = bm0 + (i >> 2) * 64 + ty * 4 + (i & 3);
#pragma unroll
    for (int j = 0; j < 8; j++) cols[j] = bn0 + (j >> 2) * 64 + tx * 4 + (j & 3);
    float bs[8];
#pragma unroll
    for (int j = 0; j < 8; j++) {
        bs[j] = 0.f;
        if (cols[j] < N) {
            if (b1) bs[j] += b1[cols[j]];
            if (b2) bs[j] += b2[cols[j]];
        }
    }
#pragma unroll
    for (int i = 0; i < 8; i++) {
        float* crow = C + (size_t)rows[i] * N;
#pragma unroll
        for (int j = 0; j < 8; j += 2) {
            if (cols[j] < N) {
                float2 v = {acc[i][j] + bs[j], acc[i][j + 1] + bs[j + 1]};
                *(float2*)(crow + cols[j]) = v;
            }
        }
    }
}

// ---------------------------------------------------------------------------
// Fused LSTM step: gates = xp + h_in @ Whh^T, then pointwise LSTM update.
// Block computes [BM=16 batch rows] x [BN=32 hidden cols] for all 4 gates.
// Grid: (ceil(H/32), 8). 256 threads; thread tile = 1 row x 2 cols x 4 gates.
// h_in is read-only (previous timestep buffer); h_out is a different buffer
// (the y-sequence slot for t), so no read/write race. c updated in place
// (tile-private elements only).
// Gate order (rows of Whh / cols of xp): i, f, g, o.
// ---------------------------------------------------------------------------
#define SBN 32
#define SBK 32

__global__ __launch_bounds__(256) void lstm_step(
    const float* __restrict__ xp,   // [B_, H4] for this timestep
    const float* __restrict__ Whh,  // [4H, H]
    const float* __restrict__ h_in, // [B_, H]
    float* __restrict__ c,          // [B_, H] in/out
    float* __restrict__ h_out,      // [B_, H]
    int H, int H4)
{
    __shared__ float Hs[SBK][16];
    __shared__ float Ws[4][SBK][SBN];
    const int tid = threadIdx.x;
    const int tx = tid & 15;        // col pair
    const int ty = tid >> 4;        // 0..15 row
    const int bn0 = blockIdx.x * SBN;
    const int bm0 = blockIdx.y * 16;

    float acc[4][2];
#pragma unroll
    for (int g = 0; g < 4; g++) { acc[g][0] = 0.f; acc[g][1] = 0.f; }

    // load indices
    const int hr = tid & 15;          // 0..15
    const int hk = (tid >> 4) * 2;    // 0..30
    const int wg = tid >> 6;          // 0..3
    const int wc = (tid & 63) >> 1;   // 0..31
    const int wk = (tid & 1) * 16;    // 0 or 16

    const float* hrow = h_in + (size_t)(bm0 + hr) * H;
    const int wcol = bn0 + wc;
    const bool wcv = (wcol < H);
    const float* wrow = Whh + (size_t)(wg * H + (wcv ? wcol : 0)) * H;

    for (int k0 = 0; k0 < H; k0 += SBK) {
        float2 hv = {0.f, 0.f};
        {
            int kb = k0 + hk;
            if (kb + 2 <= H) hv = *(const float2*)(hrow + kb);
        }
        float wv[16];
#pragma unroll
        for (int p = 0; p < 16; p++) wv[p] = 0.f;
        if (wcv) {
#pragma unroll
            for (int p = 0; p < 8; p++) {
                int kb = k0 + wk + p * 2;
                if (kb + 2 <= H) {
                    float2 t = *(const float2*)(wrow + kb);
                    wv[p * 2] = t.x; wv[p * 2 + 1] = t.y;
                }
            }
        }
        __syncthreads();
        Hs[hk][hr] = hv.x; Hs[hk + 1][hr] = hv.y;
#pragma unroll
        for (int p = 0; p < 16; p++) Ws[wg][wk + p][wc] = wv[p];
        __syncthreads();
#pragma unroll
        for (int kk = 0; kk < SBK; kk++) {
            float a = Hs[kk][ty];
            float2 b0 = *(const float2*)&Ws[0][kk][tx * 2];
            float2 b1 = *(const float2*)&Ws[1][kk][tx * 2];
            float2 b2 = *(const float2*)&Ws[2][kk][tx * 2];
            float2 b3 = *(const float2*)&Ws[3][kk][tx * 2];
            acc[0][0] += a * b0.x; acc[0][1] += a * b0.y;
            acc[1][0] += a * b1.x; acc[1][1] += a * b1.y;
            acc[2][0] += a * b2.x; acc[2][1] += a * b2.y;
            acc[3][0] += a * b3.x; acc[3][1] += a * b3.y;
        }
    }

    const int m = bm0 + ty;
    const int n = bn0 + tx * 2;
    if (n < H) {   // H even, n even -> pair fully valid
        const float* xr = xp + (size_t)m * H4;
        float2 xi = *(const float2*)(xr + n);
        float2 xf = *(const float2*)(xr + H + n);
        float2 xg = *(const float2*)(xr + 2 * H + n);
        float2 xo = *(const float2*)(xr + 3 * H + n);
        size_t idx = (size_t)m * H + n;
        float2 cv = *(const float2*)(c + idx);

        float2 hvo, cvo;
        {
            float gi = acc[0][0] + xi.x, gf = acc[1][0] + xf.x;
            float gg = acc[2][0] + xg.x, go = acc[3][0] + xo.x;
            float si = 1.f / (1.f + expf(-gi));
            float sf = 1.f / (1.f + expf(-gf));
            float tg = tanhf(gg);
            float so = 1.f / (1.f + expf(-go));
            float cn = sf * cv.x + si * tg;
            cvo.x = cn; hvo.x = so * tanhf(cn);
        }
        {
            float gi = acc[0][1] + xi.y, gf = acc[1][1] + xf.y;
            float gg = acc[2][1] + xg.y, go = acc[3][1] + xo.y;
            float si = 1.f / (1.f + expf(-gi));
            float sf = 1.f / (1.f + expf(-gf));
            float tg = tanhf(gg);
            float so = 1.f / (1.f + expf(-go));
            float cn = sf * cv.y + si * tg;
            cvo.y = cn; hvo.y = so * tanhf(cn);
        }
        *(float2*)(c + idx) = cvo;
        *(float2*)(h_out + idx) = hvo;
    }
}

// ---------------------------------------------------------------------------
// Host launcher
// ---------------------------------------------------------------------------
extern "C" void kernel_launch(void* const* d_in, const int* in_sizes, int n_in,
                              void* d_out, int out_size, void* d_ws, size_t ws_size,
                              hipStream_t stream) {
    const int*   tokens = (const int*)  d_in[0];
    const float* h0_0   = (const float*)d_in[1];
    const float* c0_0   = (const float*)d_in[2];
    const float* h0_1   = (const float*)d_in[3];
    const float* c0_1   = (const float*)d_in[4];
    const float* h0_2   = (const float*)d_in[5];
    const float* c0_2   = (const float*)d_in[6];
    const float* embW   = (const float*)d_in[7];
    const float* W_ih0  = (const float*)d_in[8];
    const float* W_hh0  = (const float*)d_in[9];
    const float* b_ih0  = (const float*)d_in[10];
    const float* b_hh0  = (const float*)d_in[11];
    const float* W_ih1  = (const float*)d_in[12];
    const float* W_hh1  = (const float*)d_in[13];
    const float* b_ih1  = (const float*)d_in[14];
    const float* b_hh1  = (const float*)d_in[15];
    const float* W_ih2  = (const float*)d_in[16];
    const float* W_hh2  = (const float*)d_in[17];
    const float* b_ih2  = (const float*)d_in[18];
    const float* b_hh2  = (const float*)d_in[19];
    const float* dec_b  = (const float*)d_in[20];
    float* out = (float*)d_out;

    // Workspace layout (floats). Total = 69,139,200 floats = 276.6 MB.
    float* ws   = (float*)d_ws;
    float* emb  = ws;                            // 8960*400
    float* y0   = emb + (size_t)8960 * 400;      // 8960*1150
    float* y1   = y0  + (size_t)8960 * 1150;     // 8960*1150
    float* y2   = y1  + (size_t)8960 * 1150;     // 8960*400
    float* xp   = y2  + (size_t)8960 * 400;      // 8960*4600
    float* cbuf = xp  + (size_t)8960 * 4600;     // 128*1150

    const size_t stepH  = (size_t)B_ * H_;   // 147200
    const size_t stepE  = (size_t)B_ * E_;   // 51200
    const size_t step4H = (size_t)B_ * 4 * H_;
    const size_t step4E = (size_t)B_ * 4 * E_;

    // 1. Embedding
    emb_gather<<<T_ * B_, 256, 0, stream>>>(tokens, embW, emb);

    // 2. Layer 0
    {
        dim3 g((4 * H_ + GBN - 1) / GBN, (T_ * B_) / GBM);
        sgemm_nt<<<g, 256, 0, stream>>>(emb, W_ih0, b_ih0, b_hh0, xp,
                                        T_ * B_, 4 * H_, E_);
        hipMemcpyAsync(cbuf, c0_0, sizeof(float) * stepH,
                       hipMemcpyDeviceToDevice, stream);
        dim3 sg((H_ + SBN - 1) / SBN, B_ / 16);
        for (int t = 0; t < T_; t++) {
            const float* hin = (t == 0) ? h0_0 : (y0 + (size_t)(t - 1) * stepH);
            lstm_step<<<sg, 256, 0, stream>>>(xp + (size_t)t * step4H, W_hh0,
                                              hin, cbuf, y0 + (size_t)t * stepH,
                                              H_, 4 * H_);
        }
    }

    // 3. Layer 1
    {
        dim3 g((4 * H_ + GBN - 1) / GBN, (T_ * B_) / GBM);
        sgemm_nt<<<g, 256, 0, stream>>>(y0, W_ih1, b_ih1, b_hh1, xp,
                                        T_ * B_, 4 * H_, H_);
        hipMemcpyAsync(cbuf, c0_1, sizeof(float) * stepH,
                       hipMemcpyDeviceToDevice, stream);
        dim3 sg((H_ + SBN - 1) / SBN, B_ / 16);
        for (int t = 0; t < T_; t++) {
            const float* hin = (t == 0) ? h0_1 : (y1 + (size_t)(t - 1) * stepH);
            lstm_step<<<sg, 256, 0, stream>>>(xp + (size_t)t * step4H, W_hh1,
                                              hin, cbuf, y1 + (size_t)t * stepH,
                                              H_, 4 * H_);
        }
    }

    // 4. Layer 2 (hidden size E)
    {
        dim3 g((4 * E_ + GBN - 1) / GBN, (T_ * B_) / GBM);
        sgemm_nt<<<g, 256, 0, stream>>>(y1, W_ih2, b_ih2, b_hh2, xp,
                                        T_ * B_, 4 * E_, H_);
        hipMemcpyAsync(cbuf, c0_2, sizeof(float) * stepE,
                       hipMemcpyDeviceToDevice, stream);
        dim3 sg((E_ + SBN - 1) / SBN, B_ / 16);
        for (int t = 0; t < T_; t++) {
            const float* hin = (t == 0) ? h0_2 : (y2 + (size_t)(t - 1) * stepE);
            lstm_step<<<sg, 256, 0, stream>>>(xp + (size_t)t * step4E, W_hh2,
                                              hin, cbuf, y2 + (size_t)t * stepE,
                                              E_, 4 * E_);
        }
    }

    // 5. Tied decoder: out = y2 @ embW^T + dec_b
    {
        dim3 g((V_ + GBN - 1) / GBN, (T_ * B_) / GBM);
        sgemm_nt<<<g, 256, 0, stream>>>(y2, embW, dec_b, nullptr, out,
                                        T_ * B_, V_, E_);
    }
}